// Round 8
// baseline (271.049 us; speedup 1.0000x reference)
//
#include <hip/hip_runtime.h>

#define N_NODES 50000
#define N_EDGES 800000
#define FEATS 128
#define NCHUNK 196            // ceil(50000/256)
#define CPAD 50176            // NCHUNK*256 (loc padded)
#define GEMM_BX 196
#define GEMM_BLOCKS 392       // 196 qv-merged + 196 k
#define SCAT_BLOCKS 3125      // 3125*256 = 800000 exactly
#define NTILE 782             // ceil(50000/64)
#define NF_WAVES 8192
#define STAT_BLOCKS 256
#define HIST_BLOCKS 512       // 128 segments x 4 quarter-ranges
#define HSEG 128
#define ESEG 6250
#define HQ 12544              // bins per quarter (4*12544 = 50176 = CPAD)
#define CPQ 49                // chunks per quarter (12544/256)
#define NPART 256             // stats partial rows

typedef __attribute__((ext_vector_type(8))) short bf16x8;
typedef __attribute__((ext_vector_type(4))) float f32x4;
typedef __attribute__((ext_vector_type(2))) float f32x2;
typedef union { uint4 u; bf16x8 v; } pack8;

__device__ __forceinline__ unsigned short f2bf(float f){
  unsigned u = __float_as_uint(f);
  u += 0x7FFF + ((u >> 16) & 1);           // RNE
  return (unsigned short)(u >> 16);
}
// HW packed f32->bf16 (RNE), 2 values / inst
__device__ __forceinline__ unsigned cvtpk(float lo, float hi){
  unsigned r;
  asm("v_cvt_pk_bf16_f32 %0, %1, %2" : "=v"(r) : "v"(lo), "v"(hi));
  return r;
}
// packed dual-f32 math (VOP3P, gfx90a+): 2 FLOPs/inst
__device__ __forceinline__ f32x2 pk_fma(f32x2 a, f32x2 b, f32x2 c){
  f32x2 d;
  asm("v_pk_fma_f32 %0, %1, %2, %3" : "=v"(d) : "v"(a), "v"(b), "v"(c));
  return d;
}
__device__ __forceinline__ f32x2 pk_add(f32x2 a, f32x2 b){
  f32x2 d;
  asm("v_pk_add_f32 %0, %1, %2" : "=v"(d) : "v"(a), "v"(b));
  return d;
}
__device__ __forceinline__ f32x2 pk_mul(f32x2 a, f32x2 b){
  f32x2 d;
  asm("v_pk_mul_f32 %0, %1, %2" : "=v"(d) : "v"(a), "v"(b));
  return d;
}
// bf16 pair unpack into f32x2 pairs (halves written independently -> no movs)
__device__ __forceinline__ void unpack8p(uint4 p, f32x2* f){
  f[0].x=__uint_as_float(p.x << 16); f[0].y=__uint_as_float(p.x & 0xffff0000u);
  f[1].x=__uint_as_float(p.y << 16); f[1].y=__uint_as_float(p.y & 0xffff0000u);
  f[2].x=__uint_as_float(p.z << 16); f[2].y=__uint_as_float(p.z & 0xffff0000u);
  f[3].x=__uint_as_float(p.w << 16); f[3].y=__uint_as_float(p.w & 0xffff0000u);
}

// ---------------- node 1: BN stats (plain psum partials) + bf16 q-emit (0..255) || quarter-hist (256..767)
__global__ __launch_bounds__(256) void stats_hist_kernel(
    const float* __restrict__ ftq, const float* __restrict__ ftk,
    float* __restrict__ psum, unsigned short* __restrict__ xqb,
    const int* __restrict__ dstE, unsigned short* __restrict__ rankE,
    unsigned short* __restrict__ hmat, unsigned short* __restrict__ ctot){
  __shared__ float red[4*FEATS];               // 2 KB
  __shared__ unsigned lh[HQ/2];                // 12544 u16 bins packed -> 25088 B
  int tid = threadIdx.x, bid = blockIdx.x;
  if (bid < STAT_BLOCKS){
    for (int i = tid; i < 4*FEATS; i += 256) red[i] = 0.f;
    __syncthreads();
    int sub = tid >> 5, c4 = tid & 31;         // 32 lanes cover one 128-f row
    const float* Xs = (sub < 4) ? ftq : ftk;
    int so = (sub < 4) ? 0 : 2*FEATS;
    bool isq = (sub < 4);
    float a0=0,a1=0,a2=0,a3=0,b0=0,b1=0,b2=0,b3=0;
    #pragma unroll 4
    for (int r = bid*4 + (sub&3); r < N_NODES; r += STAT_BLOCKS*4){
      float4 x = *(const float4*)(Xs + (size_t)r*FEATS + c4*4);
      if (isq)  // bf16 A rows for qv GEMM plane (same RNE as GEMM-side cvt)
        *(uint2*)&xqb[(size_t)r*FEATS + c4*4] = make_uint2(cvtpk(x.x,x.y), cvtpk(x.z,x.w));
      a0+=x.x; b0+=x.x*x.x; a1+=x.y; b1+=x.y*x.y;
      a2+=x.z; b2+=x.z*x.z; a3+=x.w; b3+=x.w*x.w;
    }
    a0 += __shfl_xor(a0,32); a1 += __shfl_xor(a1,32);
    a2 += __shfl_xor(a2,32); a3 += __shfl_xor(a3,32);
    b0 += __shfl_xor(b0,32); b1 += __shfl_xor(b1,32);
    b2 += __shfl_xor(b2,32); b3 += __shfl_xor(b3,32);
    if ((tid & 63) < 32){
      int c0 = c4*4;
      atomicAdd(&red[so + c0+0], a0); atomicAdd(&red[so + c0+1], a1);
      atomicAdd(&red[so + c0+2], a2); atomicAdd(&red[so + c0+3], a3);
      atomicAdd(&red[so + FEATS + c0+0], b0); atomicAdd(&red[so + FEATS + c0+1], b1);
      atomicAdd(&red[so + FEATS + c0+2], b2); atomicAdd(&red[so + FEATS + c0+3], b3);
    }
    __syncthreads();
    for (int i = tid; i < 4*FEATS; i += 256) psum[(size_t)bid*512 + i] = red[i];  // plain stores
  } else {
    int hb = bid - STAT_BLOCKS;                // 0..511
    int seg = hb >> 2, q = hb & 3;
    int dlo = q * HQ;
    for (int i = tid; i < HQ/2; i += 256) lh[i] = 0;
    __syncthreads();
    int e0 = seg * ESEG;
    for (int t = e0 + tid; t < e0 + ESEG; t += 256){
      int d = dstE[t] - dlo;
      if ((unsigned)d < (unsigned)HQ){
        unsigned sh = (d & 1) * 16;
        unsigned old = atomicAdd(&lh[d >> 1], 1u << sh);
        rankE[t] = (unsigned short)((old >> sh) & 0xffffu);   // local rank in (seg,d)
      }
    }
    __syncthreads();
    unsigned* row = (unsigned*)(hmat + (size_t)hb * HQ);
    for (int i = tid; i < HQ/2; i += 256) row[i] = lh[i];
    // per-chunk totals -> ctot (plain stores, no atomics)
    int wv = tid >> 6, ln = tid & 63;
    for (int c = wv; c < CPQ; c += 4){
      unsigned w0 = lh[c*128 + ln];
      unsigned w1 = lh[c*128 + 64 + ln];
      unsigned t = (w0 & 0xffffu) + (w0 >> 16) + (w1 & 0xffffu) + (w1 >> 16);
      #pragma unroll
      for (int o = 1; o < 64; o <<= 1) t += __shfl_xor((int)t, o);
      if (ln == 0) ctot[hb*CPQ + c] = (unsigned short)t;   // total <= 6250 fits u16
    }
  }
}

// ---------------- node 2: colscan + chunk scan (0..195) || BN-fold from psum (196..291) || bscan (292)
__global__ __launch_bounds__(256) void colscan_fold_kernel(
    const unsigned short* __restrict__ hmat, unsigned short* __restrict__ hbase,
    int* __restrict__ loc, const unsigned short* __restrict__ ctot, int* __restrict__ bscan,
    const float* __restrict__ Wq, const float* __restrict__ bq,
    const float* __restrict__ Wk, const float* __restrict__ Wv,
    const float* __restrict__ gq, const float* __restrict__ bqn,
    const float* __restrict__ gk, const float* __restrict__ bkn,
    const float* __restrict__ psum,
    unsigned short* __restrict__ Wb, float* __restrict__ bias){
  __shared__ int s[256];
  int tid = threadIdx.x, bid = blockIdx.x;
  if (bid < NCHUNK){
    int q = bid / CPQ;                         // chunks never straddle quarters (49*256=12544)
    int d = bid*256 + tid;
    int col = d - q*HQ;
    const unsigned short* hp = hmat + (size_t)q*HQ + col;   // row hb = seg*4+q
    unsigned short* bp = hbase + (size_t)q*HQ + col;
    int run = 0;
    #pragma unroll 8
    for (int sg = 0; sg < HSEG; sg++){
      int v = hp[(size_t)sg*4*HQ];
      bp[(size_t)sg*4*HQ] = (unsigned short)run;   // exclusive prefix over segments
      run += v;
    }
    s[tid] = run; __syncthreads();
    for (int dd = 1; dd < 256; dd <<= 1){
      int tv = (tid >= dd) ? s[tid-dd] : 0; __syncthreads();
      s[tid] += tv; __syncthreads();
    }
    loc[d] = s[tid] - run;                     // chunk-local exclusive
  } else if (bid == NCHUNK + 96){              // bscan block: reduce ctot, ladder-scan
    int v = 0;
    if (tid < NCHUNK){
      int q = tid / CPQ, cc = tid - q*CPQ;
      const unsigned short* cp = ctot + q*CPQ + cc;   // row hb = seg*4+q
      #pragma unroll 8
      for (int sg = 0; sg < HSEG; sg++) v += cp[(size_t)sg*4*CPQ];
    }
    s[tid] = v; __syncthreads();
    for (int dd = 1; dd < 256; dd <<= 1){
      int tv = (tid >= dd) ? s[tid-dd] : 0; __syncthreads();
      s[tid] += tv; __syncthreads();
    }
    if (tid < NCHUNK) bscan[tid] = s[tid] - v;
  } else {
    int wv = (bid - NCHUNK)*4 + (tid >> 6);    // 0..383
    int lane = tid & 63;
    int m = wv >> 7;                           // 0=q,1=v,2=k
    int o = wv & 127;
    const float* Wsrc = (m==0) ? Wq : (m==1) ? Wv : Wk;
    const float* g   = (m==2) ? gk : gq;
    const float* bb  = (m==2) ? bkn : bqn;
    int base = (m==2) ? 2*FEATS : 0;
    const float invN = 1.0f / (float)N_NODES;
    int i0 = lane*2;
    // reduce 256 partial rows (coalesced float2 columns, L2-resident)
    float2 sm = make_float2(0.f,0.f), sv = make_float2(0.f,0.f);
    const float* pp = psum + base + i0;
    for (int p = 0; p < NPART; p++){
      float2 a = *(const float2*)(pp + (size_t)p*512);
      float2 b = *(const float2*)(pp + (size_t)p*512 + FEATS);
      sm.x += a.x; sm.y += a.y; sv.x += b.x; sv.y += b.y;
    }
    float acc = 0.f;
    unsigned short w2[2];
    #pragma unroll
    for (int t = 0; t < 2; t++){
      float sms = t ? sm.y : sm.x;
      float svs = t ? sv.y : sv.x;
      int i = i0 + t;
      float mean = sms*invN;
      float var  = svs*invN - mean*mean;
      float rstd = rsqrtf(var + 1e-5f);
      float scale = g[i]*rstd;
      float shift = bb[i] - mean*scale;
      float w = Wsrc[o*FEATS + i];
      w2[t] = f2bf(w*scale);
      acc += shift*w;
    }
    ((unsigned*)Wb)[(m*FEATS*FEATS + o*FEATS + i0) >> 1] =
        (unsigned)w2[0] | ((unsigned)w2[1] << 16);
    #pragma unroll
    for (int off = 1; off < 64; off <<= 1) acc += __shfl_xor(acc, off);
    if (lane == 0) bias[m*FEATS + o] = acc + ((m==0) ? bq[o] : 0.f);
  }
}

// ---------------- node 3: fully atomic-free CSR scatter (no LDS, tiny VGPR -> full occupancy)
__global__ __launch_bounds__(256) void scatter_kernel(
    const int* __restrict__ dstE, const int* __restrict__ srcE,
    const int* __restrict__ loc, const int* __restrict__ bscan,
    const unsigned short* __restrict__ rankE, const unsigned short* __restrict__ hbase,
    int* __restrict__ src_csr){
  int t = blockIdx.x*256 + threadIdx.x;        // exactly covers N_EDGES
  int d = dstE[t];
  int seg = t / ESEG;
  int q = d / HQ;
  int base = (int)hbase[(size_t)(seg*4 + q)*HQ + (d - q*HQ)];
  src_csr[loc[d] + bscan[d >> 8] + base + (int)rankE[t]] = srcE[t];
}

// ---------------- node 4: merged-plane GEMM
__global__ __launch_bounds__(256) void gemm_kernel(
    const unsigned short* __restrict__ xqb, const float* __restrict__ ftk,
    const unsigned short* __restrict__ Wball, const float* __restrict__ biasall,
    unsigned short* __restrict__ qv, unsigned short* __restrict__ kb){
  __shared__ unsigned short Bs[2][FEATS][FEATS];   // 64KB, XOR-swizzled 16B chunks
  int tid = threadIdx.x, bid = blockIdx.x;
  int isk = (bid >= GEMM_BX);
  int bx = isk ? bid - GEMM_BX : bid;
  int nplanes = isk ? 1 : 2;
  { // stage B plane(s) with chunk-XOR swizzle: chunk' = chunk ^ (row&15)
    for (int p = 0; p < nplanes; p++){
      int m = isk ? 2 : p;
      const uint4* srcp = (const uint4*)(Wball + m*FEATS*FEATS);
      for (int idx = tid; idx < FEATS*FEATS/8; idx += 256){
        int n = idx >> 4, ck = idx & 15;
        *(uint4*)&Bs[p][n][(ck ^ (n & 15))*8] = srcp[idx];
      }
    }
  }
  __syncthreads();                              // only barrier in the kernel
  int wave = tid >> 6, lane = tid & 63;
  int mrow = lane & 15, quad = lane >> 4;
  float bv[2][8];
  #pragma unroll
  for (int p = 0; p < 2; p++)
    #pragma unroll
    for (int ct = 0; ct < 8; ct++)
      bv[p][ct] = biasall[(isk ? 2 : p)*FEATS + ct*16 + mrow];
  uint4 cur[4], nxt[4];
  auto loadA = [&](uint4* buf, int t){
    int arow = t*64 + wave*16 + mrow;
    if (!isk){
      const unsigned short* xp = xqb + (size_t)arow*FEATS + quad*8;  // padded rows
      buf[0] = *(const uint4*)xp;
      buf[1] = *(const uint4*)(xp + 32);
      buf[2] = *(const uint4*)(xp + 64);
      buf[3] = *(const uint4*)(xp + 96);
    } else {
      bool rok = arow < N_NODES;
      const float* xp = ftk + (size_t)(rok ? arow : 0)*FEATS + quad*8;
      #pragma unroll
      for (int kt = 0; kt < 4; kt++){
        float4 x0 = *(const float4*)(xp + kt*32);
        float4 x1 = *(const float4*)(xp + kt*32 + 4);
        if (!rok){ x0 = make_float4(0.f,0.f,0.f,0.f); x1 = x0; }
        buf[kt].x = cvtpk(x0.x, x0.y); buf[kt].y = cvtpk(x0.z, x0.w);
        buf[kt].z = cvtpk(x1.x, x1.y); buf[kt].w = cvtpk(x1.z, x1.w);
      }
    }
  };
  loadA(cur, bx);
  for (int t = bx; t < NTILE; t += GEMM_BX){
    int tn = t + GEMM_BX;
    if (tn < NTILE) loadA(nxt, tn);             // prefetch next A tile under MFMA
    f32x4 acc[2][8];
    #pragma unroll
    for (int p = 0; p < 2; p++)
      #pragma unroll
      for (int i = 0; i < 8; i++) acc[p][i] = (f32x4){0.f,0.f,0.f,0.f};
    #pragma unroll
    for (int kt = 0; kt < 4; kt++){
      pack8 a; a.u = cur[kt];
      #pragma unroll
      for (int ct = 0; ct < 8; ct++){
        bf16x8 b0 = *(bf16x8*)&Bs[0][ct*16 + mrow][((kt*4 + quad) ^ mrow)*8];
        acc[0][ct] = __builtin_amdgcn_mfma_f32_16x16x32_bf16(a.v, b0, acc[0][ct], 0, 0, 0);
      }
      if (!isk){
        #pragma unroll
        for (int ct = 0; ct < 8; ct++){
          bf16x8 b1 = *(bf16x8*)&Bs[1][ct*16 + mrow][((kt*4 + quad) ^ mrow)*8];
          acc[1][ct] = __builtin_amdgcn_mfma_f32_16x16x32_bf16(a.v, b1, acc[1][ct], 0, 0, 0);
        }
      }
    }
    int row0 = t*64;
    #pragma unroll
    for (int p = 0; p < 2; p++){
      if (isk && p) break;
      unsigned short* Out = isk ? kb : (qv + p*128);
      const int ostride = isk ? FEATS : 256;
      #pragma unroll
      for (int ct = 0; ct < 8; ct++){
        int col = ct*16 + mrow;
        #pragma unroll
        for (int v = 0; v < 4; v++){
          int orow = row0 + wave*16 + quad*4 + v;
          float sv = acc[p][ct][v] + bv[p][ct];
          float pf = __shfl_xor(sv, 1);         // partner col's f32 sum
          if (!(mrow & 1) && orow < N_NODES)
            *(unsigned*)&Out[(size_t)orow*ostride + col] = cvtpk(sv, pf);
        }
      }
    }
    #pragma unroll
    for (int i = 0; i < 4; i++) cur[i] = nxt[i];
  }
}

// ---------------- node 5: per-dst-node scores + max-free softmax agg (packed dual-f32 math)
__global__ __launch_bounds__(256) void node_fused_kernel(
    const unsigned short* __restrict__ qv, const unsigned short* __restrict__ kb,
    const float* __restrict__ attn, const int* __restrict__ src_csr,
    const int* __restrict__ loc, const int* __restrict__ bscan,
    float* __restrict__ out){
  int tid = threadIdx.x;
  int lane = tid & 63;
  int h = lane & 7, g = lane >> 3;
  int w = blockIdx.x*4 + (tid >> 6);
  const float L2E = 1.44269504f;
  const f32x2 nL2 = {-L2E, -L2E};
  const f32x2 one2 = {1.f, 1.f};
  f32x2 arp[8];
  {
    const float4* ap = (const float4*)(attn + h*16);
    float4 a0 = ap[0], a1 = ap[1], a2 = ap[2], a3 = ap[3];
    arp[0].x=a0.x; arp[0].y=a0.y; arp[1].x=a0.z; arp[1].y=a0.w;
    arp[2].x=a1.x; arp[2].y=a1.y; arp[3].x=a1.z; arp[3].y=a1.w;
    arp[4].x=a2.x; arp[4].y=a2.y; arp[5].x=a2.z; arp[5].y=a2.w;
    arp[6].x=a3.x; arp[6].y=a3.y; arp[7].x=a3.z; arp[7].y=a3.w;
  }
  for (int n = w; n < N_NODES; n += NF_WAVES){
    int off0 = loc[n]   + bscan[n>>8];
    int off1 = loc[n+1] + bscan[(n+1)>>8];      // loc[50000] valid (padded chunk 195)
    int deg = off1 - off0;
    if (deg == 0){
      ((float2*)(out + (size_t)n*FEATS))[lane] = make_float2(0.f, 0.f);
      continue;
    }
    f32x2 kf2p[8];
    {
      const unsigned short* kr = kb + (size_t)n*FEATS + h*16;
      uint4 k0 = *(const uint4*)kr;
      uint4 k1 = *(const uint4*)(kr + 8);
      f32x2 kp[8]; unpack8p(k0, kp); unpack8p(k1, kp+4);
      #pragma unroll
      for (int j = 0; j < 8; j++) kf2p[j] = pk_mul(kp[j], nL2);
    }
    float ssum = 0.f;
    f32x2 acc2[8];
    #pragma unroll
    for (int j = 0; j < 8; j++){ acc2[j].x = 0.f; acc2[j].y = 0.f; }
    if (g < deg){
      int sA = src_csr[off0 + g];
      int jB = g + 8;
      int sB = (jB < deg) ? src_csr[off0 + jB] : sA;   // dup tail -> L1 hit
      const unsigned short* pA = qv + (size_t)sA*256 + h*16;
      uint4 qa0 = *(const uint4*)pA;
      uint4 qa1 = *(const uint4*)(pA + 8);
      while (true){
        uint4 va0 = *(const uint4*)(pA + 128);   // current v (interleaved row)
        uint4 va1 = *(const uint4*)(pA + 136);
        const unsigned short* pB = qv + (size_t)sB*256 + h*16;
        uint4 qb0 = *(const uint4*)pB;           // next q prefetch
        uint4 qb1 = *(const uint4*)(pB + 8);
        int jC = jB + 8;
        int sC = (jC < deg) ? src_csr[off0 + jC] : sB;
        f32x2 qp[8]; unpack8p(qa0, qp); unpack8p(qa1, qp+4);
        float ta = 0.f, tb = 0.f, tc = 0.f, td = 0.f;
        #pragma unroll
        for (int j = 0; j < 8; j++){
          f32x2 xs = pk_fma(qp[j], nL2, kf2p[j]);          // -L2E*(q+k)
          f32x2 ep;
          ep.x = __builtin_amdgcn_exp2f(xs.x);
          ep.y = __builtin_amdgcn_exp2f(xs.y);
          f32x2 dp = pk_add(ep, one2);                     // 1 + 2^xs
          float sl = __builtin_amdgcn_rcpf(dp.x);
          float sh = __builtin_amdgcn_rcpf(dp.y);
          if (j & 1){ tc = fmaf(arp[j].x, sl, tc); td = fmaf(arp[j].y, sh, td); }
          else      { ta = fmaf(arp[j].x, sl, ta); tb = fmaf(arp[j].y, sh, tb); }
        }
        float t = (ta + tb) + (tc + td);
        float ex = __builtin_amdgcn_exp2f(t * L2E);   // |t|<=sum|attn| -> max-free safe
        ssum += ex;
        f32x2 exx; exx.x = ex; exx.y = ex;
        f32x2 vp[8]; unpack8p(va0, vp); unpack8p(va1, vp+4);
        #pragma unroll
        for (int j = 0; j < 8; j++) acc2[j] = pk_fma(exx, vp[j], acc2[j]);
        if (jB >= deg) break;
        qa0 = qb0; qa1 = qb1; pA = pB;
        jB = jC; sB = sC;
      }
    }
    ssum += __shfl_xor(ssum, 8); ssum += __shfl_xor(ssum, 16); ssum += __shfl_xor(ssum, 32);
    #pragma unroll
    for (int j = 0; j < 8; j++){
      acc2[j].x += __shfl_xor(acc2[j].x, 8);
      acc2[j].x += __shfl_xor(acc2[j].x, 16);
      acc2[j].x += __shfl_xor(acc2[j].x, 32);
      acc2[j].y += __shfl_xor(acc2[j].y, 8);
      acc2[j].y += __shfl_xor(acc2[j].y, 16);
      acc2[j].y += __shfl_xor(acc2[j].y, 32);
    }
    if (g == 0){
      float inv_s = 1.f / ssum;
      float4* op = (float4*)(out + (size_t)n*FEATS + h*16);
      op[0] = make_float4(acc2[0].x*inv_s, acc2[0].y*inv_s, acc2[1].x*inv_s, acc2[1].y*inv_s);
      op[1] = make_float4(acc2[2].x*inv_s, acc2[2].y*inv_s, acc2[3].x*inv_s, acc2[3].y*inv_s);
      op[2] = make_float4(acc2[4].x*inv_s, acc2[4].y*inv_s, acc2[5].x*inv_s, acc2[5].y*inv_s);
      op[3] = make_float4(acc2[6].x*inv_s, acc2[6].y*inv_s, acc2[7].x*inv_s, acc2[7].y*inv_s);
    }
  }
}

extern "C" void kernel_launch(void* const* d_in, const int* in_sizes, int n_in,
                              void* d_out, int out_size, void* d_ws, size_t ws_size,
                              hipStream_t stream){
  (void)in_sizes; (void)n_in; (void)out_size; (void)ws_size;
  const float* ftq  = (const float*)d_in[0];
  const float* ftk  = (const float*)d_in[1];
  const int*   srcE = (const int*)d_in[2];
  const int*   dstE = (const int*)d_in[3];
  const float* Wq   = (const float*)d_in[4];
  const float* bq   = (const float*)d_in[5];
  const float* Wk   = (const float*)d_in[6];
  const float* Wv   = (const float*)d_in[7];
  const float* attn = (const float*)d_in[8];
  const float* gq   = (const float*)d_in[9];
  const float* bqn  = (const float*)d_in[10];
  const float* gk   = (const float*)d_in[11];
  const float* bkn  = (const float*)d_in[12];

  char* ws = (char*)d_ws;
  float* psum    = (float*)(ws + 0);             // 256*512 f -> 524288  (fully written, no memset)
  int*   bscan   = (int*)(ws + 524288);          // 196 i     -> 525072
  int*   loc     = (int*)(ws + 525312);          // CPAD i    -> 726016
  int*   src_csr = (int*)(ws + 726016);          // 800000 i  -> 3926016
  unsigned short* rankE = (unsigned short*)(ws + 3926016);   // 800000 u16 -> 5526016
  unsigned short* hmat  = (unsigned short*)(ws + 5526016);   // 512*12544 u16 -> 18371072
  unsigned short* hbase = (unsigned short*)(ws + 18371072);  // 512*12544 u16 -> 31216128
  unsigned short* ctot  = (unsigned short*)(ws + 31216128);  // 512*49 u16 -> 31266304
  unsigned short* Wb    = (unsigned short*)(ws + 31266304);  // 3*16384 u16 -> 31364608
  float* biasf   = (float*)(ws + 31364608);      // 384 f -> 31366144
  unsigned short* xqb = (unsigned short*)(ws + 31366144);    // 50176*128 u16 -> 44211200
  unsigned short* qv  = (unsigned short*)(ws + 44211200);    // 50000*256 u16 -> 69811200
  unsigned short* kb  = (unsigned short*)(ws + 69811200);    // 50000*128 u16 -> 82611200
  float* out = (float*)d_out;

  // no memset: every ws buffer is fully written before it is read

  hipLaunchKernelGGL(stats_hist_kernel, dim3(STAT_BLOCKS + HIST_BLOCKS), dim3(256), 0, stream,
                     ftq, ftk, psum, xqb, dstE, rankE, hmat, ctot);
  hipLaunchKernelGGL(colscan_fold_kernel, dim3(NCHUNK + 97), dim3(256), 0, stream,
                     hmat, hbase, loc, ctot, bscan,
                     Wq, bq, Wk, Wv, gq, bqn, gk, bkn, psum, Wb, biasf);
  hipLaunchKernelGGL(scatter_kernel, dim3(SCAT_BLOCKS), dim3(256), 0, stream,
                     dstE, srcE, loc, bscan, rankE, hbase, src_csr);
  hipLaunchKernelGGL(gemm_kernel, dim3(GEMM_BLOCKS), dim3(256), 0, stream,
                     xqb, ftk, Wb, biasf, qv, kb);
  hipLaunchKernelGGL(node_fused_kernel, dim3(NF_WAVES/4), dim3(256), 0, stream,
                     qv, kb, attn, src_csr, loc, bscan, out);
}